// Round 1
// baseline (4210.586 us; speedup 1.0000x reference)
//
#include <hip/hip_runtime.h>
#include <hip/hip_cooperative_groups.h>

namespace cg = cooperative_groups;

typedef __attribute__((ext_vector_type(8))) short bf16x8;   // 8 bf16 (4 VGPRs)
typedef __attribute__((ext_vector_type(4))) float f32x4;    // MFMA acc

#define NBATCH 64
#define NH     512
#define NV     8001
#define NVP    8064      // padded V (63 tiles of 128)
#define NSTEP  128       // T-1
#define NG     2048      // 4*NH gate columns

// ---- workspace layout (bytes) ----
#define OFF_XS    ((size_t)0)
#define SZ_XS     ((size_t)NSTEP*NBATCH*NH*2)        // 8 MB  bf16 [t][b][h]
#define OFF_WP    (OFF_XS + SZ_XS)
#define SZ_WP     ((size_t)2*2048*1024*2)            // 8 MB  frag-packed [layer][lb][s][g][lane][8]
#define OFF_WDEC  (OFF_WP + SZ_WP)
#define SZ_WDEC   ((size_t)NVP*NH*2)                 // 8.26 MB bf16, zero-padded rows
#define OFF_BIAS  (OFF_WDEC + SZ_WDEC)
#define SZ_BIAS   ((size_t)2*NG*4)                   // combined b_ih+b_hh per layer, fp32
#define OFF_STATE (OFF_BIAS + SZ_BIAS)
#define SZ_STATE  ((size_t)6*NBATCH*NH*2)            // h1[2], a[2], h2[2], bf16
#define OFF_BSEQ  (OFF_STATE + SZ_STATE)
#define SZ_BSEQ   ((size_t)NSTEP*NBATCH*NH*2)        // 8 MB bf16 [t][b][h]

__device__ __forceinline__ unsigned short f2bf(float x) {  // RNE float->bf16
  union { float f; unsigned u; } v; v.f = x;
  unsigned r = v.u + 0x7FFFu + ((v.u >> 16) & 1u);
  return (unsigned short)(r >> 16);
}
__device__ __forceinline__ float sigm(float x) { return 1.f / (1.f + __expf(-x)); }

// ---------------- prep kernels ----------------

// xs[t][b][h] = bf16(emb[x[b][t]][h]), t in [0,128)
__global__ void k_xs(const int* __restrict__ x, const float* __restrict__ emb,
                     unsigned short* __restrict__ xs) {
  int idx = blockIdx.x * 256 + threadIdx.x;          // 128*64*512 threads
  int t = idx >> 15, rem = idx & 32767, b = rem >> 9, h = rem & 511;
  xs[idx] = f2bf(emb[(size_t)x[b * 129 + t] * NH + h]);
}

// wdec[v][h] bf16, zero pad rows v>=8001
__global__ void k_wdec(const float* __restrict__ W, unsigned short* __restrict__ wdec) {
  int idx = blockIdx.x * 256 + threadIdx.x;          // 8064*512 threads
  int v = idx >> 9, h = idx & 511;
  wdec[idx] = (v < NV) ? f2bf(W[(size_t)v * NH + h]) : (unsigned short)0;
}

__global__ void k_bias(const float* __restrict__ bi1, const float* __restrict__ bh1,
                       const float* __restrict__ bi2, const float* __restrict__ bh2,
                       float* __restrict__ bias) {
  int i = blockIdx.x * 256 + threadIdx.x;            // 4096 threads
  bias[i] = (i < NG) ? (bi1[i] + bh1[i]) : (bi2[i - NG] + bh2[i - NG]);
}

// Pack recurrence weights into MFMA B-fragment order.
// Layout: [layer][lb(32)][s(32)][g(4)][lane(64)][8 bf16]; r = g*512+lb*16+(lane&15), k = s*32+(lane>>4)*8
__global__ void k_wpack(const float* __restrict__ Wih1, const float* __restrict__ Whh1,
                        const float* __restrict__ Wih2, const float* __restrict__ Whh2,
                        unsigned short* __restrict__ wp) {
  int tid = blockIdx.x * 256 + threadIdx.x;          // 524288 threads
  int l = tid & 63, g = (tid >> 6) & 3, s = (tid >> 8) & 31, lb = (tid >> 13) & 31, layer = tid >> 18;
  int n = l & 15, q = l >> 4;
  int r = g * NH + lb * 16 + n;
  int k0 = s * 32 + q * 8;
  const float* Wih = layer ? Wih2 : Wih1;
  const float* Whh = layer ? Whh2 : Whh1;
  const float* src = (k0 < NH) ? (Wih + (size_t)r * NH + k0) : (Whh + (size_t)r * NH + (k0 - NH));
  unsigned short tmp[8];
#pragma unroll
  for (int j = 0; j < 8; ++j) tmp[j] = f2bf(src[j]);
  *(uint4*)(wp + (size_t)tid * 8) = *(const uint4*)tmp;
}

// ---------------- cooperative recurrence ----------------
// 64 blocks x 256. Block = (layer = bid>>5, lb = bid&31) owns features [lb*16, lb*16+16).
// Phase p: layer1 computes step t=p (p<128); layer2 computes step t=p-1 (p>=1). 1 grid sync/phase.
// State buffers double-buffered: phase p writes buf[p&1], reads buf[(p+1)&1].
__global__ void __launch_bounds__(256, 1)
k_recur(const unsigned short* __restrict__ xs, const unsigned short* __restrict__ wpack,
        const float* __restrict__ bias,
        const float* __restrict__ gamma1, const float* __restrict__ beta1, const float* __restrict__ mask1,
        const float* __restrict__ gamma2, const float* __restrict__ beta2, const float* __restrict__ mask2,
        unsigned short* __restrict__ state, unsigned short* __restrict__ bseq) {
  __shared__ unsigned short wlds[32 * 4 * 64 * 8];   // 128 KB: block's weight strip, frag order
  __shared__ float red[4][2][16];                    // BN cross-wave partials

  cg::grid_group grid = cg::this_grid();

  const int layer = blockIdx.x >> 5, lb = blockIdx.x & 31, f0 = lb * 16;
  const float* gam = layer ? gamma2 : gamma1;
  const float* bet = layer ? beta2 : beta1;
  const float* msk = layer ? mask2 : mask1;
  const float* bias_l = bias + layer * NG;
  unsigned short* h1b = state;                  // 2 x 32768
  unsigned short* ab  = state + 2 * 32768;
  unsigned short* h2b = state + 4 * 32768;

  { // stage weights -> LDS (contiguous, coalesced)
    const uint4* src = (const uint4*)(wpack + (size_t)blockIdx.x * (32 * 4 * 64 * 8));
    uint4* dst = (uint4*)wlds;
    for (int i = threadIdx.x; i < 32 * 4 * 64; i += 256) dst[i] = src[i];
  }
  __syncthreads();

  const int lane = threadIdx.x & 63, w = threadIdx.x >> 6;
  const int q = lane >> 4, n = lane & 15, m0 = w * 16;

  // per-lane invariants: feature f0+n; D rows m0+q*4+r
  const float gmv = gam[f0 + n], btv = bet[f0 + n];
  float bias_g[4], mk[4];
#pragma unroll
  for (int g = 0; g < 4; ++g) bias_g[g] = bias_l[g * NH + f0 + n];
#pragma unroll
  for (int r = 0; r < 4; ++r) mk[r] = msk[(m0 + q * 4 + r) * NH + f0 + n];

  float cst[4] = {0.f, 0.f, 0.f, 0.f};  // cell state for (row m0+q*4+r, feature f0+n)

  for (int p = 0; p <= NSTEP; ++p) {
    const int rd = (p + 1) & 1, wr = p & 1;
    const bool act = (layer == 0) ? (p < NSTEP) : (p >= 1);
    if (act) {
      const int t = (layer == 0) ? p : p - 1;
      // A operand: K 0..511 from (xs[t] | a), K 512..1023 from (h1 | h2)
      const unsigned short* A0 = (layer == 0) ? (xs + (size_t)t * 32768) : (ab + rd * 32768);
      const unsigned short* A1 = ((layer == 0) ? h1b : h2b) + rd * 32768;
      const unsigned short* rowA0 = A0 + (m0 + n) * NH;   // A-frag row = lane&15
      const unsigned short* rowA1 = A1 + (m0 + n) * NH;

      f32x4 acc[4];
#pragma unroll
      for (int g = 0; g < 4; ++g) acc[g] = (f32x4){bias_g[g], bias_g[g], bias_g[g], bias_g[g]};

#pragma unroll
      for (int s = 0; s < 32; ++s) {
        const unsigned short* ap = (s < 16) ? (rowA0 + s * 32 + q * 8)
                                            : (rowA1 + (s - 16) * 32 + q * 8);
        bf16x8 af = *(const bf16x8*)ap;
#pragma unroll
        for (int g = 0; g < 4; ++g) {
          bf16x8 bf = *(const bf16x8*)&wlds[((s * 4 + g) * 64 + lane) * 8];
          acc[g] = __builtin_amdgcn_mfma_f32_16x16x32_bf16(af, bf, acc[g], 0, 0, 0);
        }
      }

      // LSTM cell (gate order i,f,g,o), all lane-local
      float hv[4], sum = 0.f, ssq = 0.f;
#pragma unroll
      for (int r = 0; r < 4; ++r) {
        float ig = sigm(acc[0][r]), fg = sigm(acc[1][r]);
        float gg = tanhf(acc[2][r]), og = sigm(acc[3][r]);
        cst[r] = fg * cst[r] + ig * gg;
        hv[r] = og * tanhf(cst[r]);
        sum += hv[r]; ssq += hv[r] * hv[r];
      }
      // batch stats for feature f0+n: reduce over q (shfl) then waves (LDS)
      sum += __shfl_xor(sum, 16); ssq += __shfl_xor(ssq, 16);
      sum += __shfl_xor(sum, 32); ssq += __shfl_xor(ssq, 32);
      if (q == 0) { red[w][0][n] = sum; red[w][1][n] = ssq; }
      __syncthreads();
      float s1 = red[0][0][n] + red[1][0][n] + red[2][0][n] + red[3][0][n];
      float s2 = red[0][1][n] + red[1][1][n] + red[2][1][n] + red[3][1][n];
      float mu = s1 * (1.f / 64.f);
      float var = s2 * (1.f / 64.f) - mu * mu;
      float rs = rsqrtf(var + 1e-5f);

      unsigned short* hout = ((layer == 0) ? h1b : h2b) + wr * 32768;
      unsigned short* aout = (layer == 0) ? (ab + wr * 32768) : (bseq + (size_t)t * 32768);
#pragma unroll
      for (int r = 0; r < 4; ++r) {
        int row = m0 + q * 4 + r;
        float bn = (hv[r] - mu) * rs * gmv + btv;
        hout[row * NH + f0 + n] = f2bf(hv[r]);
        aout[row * NH + f0 + n] = f2bf(bn * mk[r]);
      }
    }
    __threadfence();   // release writes device-wide
    grid.sync();
    __threadfence();   // acquire (invalidate stale cached lines)
  }
}

// ---------------- decoder GEMM ----------------
// out[b][v][t] = sum_h bseq[t][b][h]*wdec[v][h] + b_dec[v]
// block (nb, b): v-tile nb*128, batch b, all 128 t. Wave w: t rows [w*32, w*32+32).
__global__ void __launch_bounds__(256)
k_dec(const unsigned short* __restrict__ bseq, const unsigned short* __restrict__ wdec,
      const float* __restrict__ bdec, float* __restrict__ out) {
  const int nb = blockIdx.x, b = blockIdx.y;
  const int n0 = nb * 128;
  const int lane = threadIdx.x & 63, w = threadIdx.x >> 6;
  const int q = lane >> 4, n = lane & 15;

  f32x4 acc[2][8];
#pragma unroll
  for (int nt = 0; nt < 8; ++nt) {
    int v = n0 + nt * 16 + n;
    float bd = (v < NV) ? bdec[v] : 0.f;
#pragma unroll
    for (int mt = 0; mt < 2; ++mt) acc[mt][nt] = (f32x4){bd, bd, bd, bd};
  }
  const unsigned short* arow[2];
#pragma unroll
  for (int mt = 0; mt < 2; ++mt) {
    int t = w * 32 + mt * 16 + n;                       // A-frag row
    arow[mt] = bseq + ((size_t)t * NBATCH + b) * NH;
  }
  const unsigned short* brow[8];
#pragma unroll
  for (int nt = 0; nt < 8; ++nt) brow[nt] = wdec + (size_t)(n0 + nt * 16 + n) * NH;

#pragma unroll 4
  for (int s = 0; s < 16; ++s) {
    bf16x8 af[2];
#pragma unroll
    for (int mt = 0; mt < 2; ++mt) af[mt] = *(const bf16x8*)(arow[mt] + s * 32 + q * 8);
#pragma unroll
    for (int nt = 0; nt < 8; ++nt) {
      bf16x8 bf = *(const bf16x8*)(brow[nt] + s * 32 + q * 8);
#pragma unroll
      for (int mt = 0; mt < 2; ++mt)
        acc[mt][nt] = __builtin_amdgcn_mfma_f32_16x16x32_bf16(af[mt], bf, acc[mt][nt], 0, 0, 0);
    }
  }
  // store: lane's 4 acc regs = 4 consecutive t -> float4 (coalesced along t)
#pragma unroll
  for (int mt = 0; mt < 2; ++mt)
#pragma unroll
    for (int nt = 0; nt < 8; ++nt) {
      int v = n0 + nt * 16 + n;
      if (v < NV) {
        int t0 = w * 32 + mt * 16 + q * 4;
        *(f32x4*)(out + ((size_t)b * NV + v) * NSTEP + t0) = acc[mt][nt];
      }
    }
}

// ---------------- launch ----------------
extern "C" void kernel_launch(void* const* d_in, const int* in_sizes, int n_in,
                              void* d_out, int out_size, void* d_ws, size_t ws_size,
                              hipStream_t stream) {
  const int*   x     = (const int*)d_in[0];
  const float* emb   = (const float*)d_in[1];
  const float* Wih1  = (const float*)d_in[2];
  const float* Whh1  = (const float*)d_in[3];
  const float* bi1   = (const float*)d_in[4];
  const float* bh1   = (const float*)d_in[5];
  const float* g1    = (const float*)d_in[6];
  const float* be1   = (const float*)d_in[7];
  const float* m1    = (const float*)d_in[8];
  const float* Wih2  = (const float*)d_in[9];
  const float* Whh2  = (const float*)d_in[10];
  const float* bi2   = (const float*)d_in[11];
  const float* bh2   = (const float*)d_in[12];
  const float* g2    = (const float*)d_in[13];
  const float* be2   = (const float*)d_in[14];
  const float* m2    = (const float*)d_in[15];
  const float* Wdec  = (const float*)d_in[16];
  const float* bdec  = (const float*)d_in[17];
  float* out = (float*)d_out;
  char* ws = (char*)d_ws;

  unsigned short* xs    = (unsigned short*)(ws + OFF_XS);
  unsigned short* wp    = (unsigned short*)(ws + OFF_WP);
  unsigned short* wdec  = (unsigned short*)(ws + OFF_WDEC);
  float*          bias  = (float*)(ws + OFF_BIAS);
  unsigned short* state = (unsigned short*)(ws + OFF_STATE);
  unsigned short* bseq  = (unsigned short*)(ws + OFF_BSEQ);

  // zero LSTM state double-buffers (ws is poisoned 0xAA before every call)
  hipMemsetAsync(state, 0, SZ_STATE, stream);

  k_xs   <<<dim3(16384), dim3(256), 0, stream>>>(x, emb, xs);
  k_wdec <<<dim3(16128), dim3(256), 0, stream>>>(Wdec, wdec);
  k_bias <<<dim3(16),    dim3(256), 0, stream>>>(bi1, bh1, bi2, bh2, bias);
  k_wpack<<<dim3(2048),  dim3(256), 0, stream>>>(Wih1, Whh1, Wih2, Whh2, wp);

  void* kargs[] = {(void*)&xs, (void*)&wp, (void*)&bias,
                   (void*)&g1, (void*)&be1, (void*)&m1,
                   (void*)&g2, (void*)&be2, (void*)&m2,
                   (void*)&state, (void*)&bseq};
  hipLaunchCooperativeKernel((void*)k_recur, dim3(64), dim3(256), kargs, 0, stream);

  k_dec<<<dim3(63, 64), dim3(256), 0, stream>>>(bseq, wdec, bdec, out);
}

// Round 2
// 3068.034 us; speedup vs baseline: 1.3724x; 1.3724x over previous
//
#include <hip/hip_runtime.h>

typedef __attribute__((ext_vector_type(8))) short bf16x8;   // 8 bf16 (4 VGPRs)
typedef __attribute__((ext_vector_type(4))) float f32x4;    // MFMA acc

#define NBATCH 64
#define NH     512
#define NV     8001
#define NVP    8064      // padded V (63 tiles of 128)
#define NSTEP  128       // T-1
#define NG     2048      // 4*NH gate columns

// ---- workspace layout (bytes) ----
#define OFF_XS    ((size_t)0)
#define SZ_XS     ((size_t)NSTEP*NBATCH*NH*2)        // 8 MB  bf16 [t][b][h]
#define OFF_WP    (OFF_XS + SZ_XS)
#define SZ_WP     ((size_t)2*2048*1024*2)            // 8 MB  frag-packed [layer][lb][s][g][lane][8]
#define OFF_WDEC  (OFF_WP + SZ_WP)
#define SZ_WDEC   ((size_t)NVP*NH*2)                 // 8.26 MB bf16, zero-padded rows
#define OFF_BIAS  (OFF_WDEC + SZ_WDEC)
#define SZ_BIAS   ((size_t)2*NG*4)                   // combined b_ih+b_hh per layer, fp32
#define OFF_STATE (OFF_BIAS + SZ_BIAS)
#define SZ_STATE  ((size_t)6*NBATCH*NH*2)            // h1[2], a[2], h2[2], bf16
#define OFF_BSEQ  (OFF_STATE + SZ_STATE)
#define SZ_BSEQ   ((size_t)NSTEP*NBATCH*NH*2)        // 8 MB bf16 [t][b][h]
#define OFF_BAR   (OFF_BSEQ + SZ_BSEQ)
#define SZ_BAR    ((size_t)256*4)                    // per-phase arrival counters

__device__ __forceinline__ unsigned short f2bf(float x) {  // RNE float->bf16
  union { float f; unsigned u; } v; v.f = x;
  unsigned r = v.u + 0x7FFFu + ((v.u >> 16) & 1u);
  return (unsigned short)(r >> 16);
}
__device__ __forceinline__ float sigm(float x) { return 1.f / (1.f + __expf(-x)); }

// ---------------- prep kernels ----------------

// xs[t][b][h] = bf16(emb[x[b][t]][h]), t in [0,128)
__global__ void k_xs(const int* __restrict__ x, const float* __restrict__ emb,
                     unsigned short* __restrict__ xs) {
  int idx = blockIdx.x * 256 + threadIdx.x;          // 128*64*512 threads
  int t = idx >> 15, rem = idx & 32767, b = rem >> 9, h = rem & 511;
  xs[idx] = f2bf(emb[(size_t)x[b * 129 + t] * NH + h]);
}

// wdec[v][h] bf16, zero pad rows v>=8001
__global__ void k_wdec(const float* __restrict__ W, unsigned short* __restrict__ wdec) {
  int idx = blockIdx.x * 256 + threadIdx.x;          // 8064*512 threads
  int v = idx >> 9, h = idx & 511;
  wdec[idx] = (v < NV) ? f2bf(W[(size_t)v * NH + h]) : (unsigned short)0;
}

__global__ void k_bias(const float* __restrict__ bi1, const float* __restrict__ bh1,
                       const float* __restrict__ bi2, const float* __restrict__ bh2,
                       float* __restrict__ bias) {
  int i = blockIdx.x * 256 + threadIdx.x;            // 4096 threads
  bias[i] = (i < NG) ? (bi1[i] + bh1[i]) : (bi2[i - NG] + bh2[i - NG]);
}

// Pack recurrence weights into MFMA B-fragment order.
// Layout: [layer][lb(32)][s(32)][g(4)][lane(64)][8 bf16]; r = g*512+lb*16+(lane&15), k = s*32+(lane>>4)*8
__global__ void k_wpack(const float* __restrict__ Wih1, const float* __restrict__ Whh1,
                        const float* __restrict__ Wih2, const float* __restrict__ Whh2,
                        unsigned short* __restrict__ wp) {
  int tid = blockIdx.x * 256 + threadIdx.x;          // 524288 threads
  int l = tid & 63, g = (tid >> 6) & 3, s = (tid >> 8) & 31, lb = (tid >> 13) & 31, layer = tid >> 18;
  int n = l & 15, q = l >> 4;
  int r = g * NH + lb * 16 + n;
  int k0 = s * 32 + q * 8;
  const float* Wih = layer ? Wih2 : Wih1;
  const float* Whh = layer ? Whh2 : Whh1;
  const float* src = (k0 < NH) ? (Wih + (size_t)r * NH + k0) : (Whh + (size_t)r * NH + (k0 - NH));
  unsigned short tmp[8];
#pragma unroll
  for (int j = 0; j < 8; ++j) tmp[j] = f2bf(src[j]);
  *(uint4*)(wp + (size_t)tid * 8) = *(const uint4*)tmp;
}

// ---------------- cooperative recurrence ----------------
// 64 blocks x 256. Block = (layer = bid>>5, lb = bid&31) owns features [lb*16, lb*16+16).
// Phase p: layer1 computes step t=p (p<128); layer2 computes step t=p-1 (p>=1). 1 barrier/phase.
// Hand-rolled barrier: per-phase counter (no reuse -> no ABA), leader atomicAdd+spin,
// exactly one release fence before arrive + one acquire fence after pass.
__global__ void __launch_bounds__(256, 1)
k_recur(const unsigned short* __restrict__ xs, const unsigned short* __restrict__ wpack,
        const float* __restrict__ bias,
        const float* __restrict__ gamma1, const float* __restrict__ beta1, const float* __restrict__ mask1,
        const float* __restrict__ gamma2, const float* __restrict__ beta2, const float* __restrict__ mask2,
        unsigned short* __restrict__ state, unsigned short* __restrict__ bseq,
        unsigned* __restrict__ bar) {
  __shared__ unsigned short wlds[32 * 4 * 64 * 8];   // 128 KB: block's weight strip, frag order
  __shared__ float red[4][2][16];                    // BN cross-wave partials

  const int layer = blockIdx.x >> 5, lb = blockIdx.x & 31, f0 = lb * 16;
  const float* gam = layer ? gamma2 : gamma1;
  const float* bet = layer ? beta2 : beta1;
  const float* msk = layer ? mask2 : mask1;
  const float* bias_l = bias + layer * NG;
  unsigned short* h1b = state;                  // 2 x 32768
  unsigned short* ab  = state + 2 * 32768;
  unsigned short* h2b = state + 4 * 32768;

  { // stage weights -> LDS (contiguous, coalesced)
    const uint4* src = (const uint4*)(wpack + (size_t)blockIdx.x * (32 * 4 * 64 * 8));
    uint4* dst = (uint4*)wlds;
    for (int i = threadIdx.x; i < 32 * 4 * 64; i += 256) dst[i] = src[i];
  }
  __syncthreads();

  const int lane = threadIdx.x & 63, w = threadIdx.x >> 6;
  const int q = lane >> 4, n = lane & 15, m0 = w * 16;

  // per-lane invariants: feature f0+n; D rows m0+q*4+r
  const float gmv = gam[f0 + n], btv = bet[f0 + n];
  float bias_g[4], mk[4];
#pragma unroll
  for (int g = 0; g < 4; ++g) bias_g[g] = bias_l[g * NH + f0 + n];
#pragma unroll
  for (int r = 0; r < 4; ++r) mk[r] = msk[(m0 + q * 4 + r) * NH + f0 + n];

  float cst[4] = {0.f, 0.f, 0.f, 0.f};  // cell state for (row m0+q*4+r, feature f0+n)

  for (int p = 0; p <= NSTEP; ++p) {
    const int rd = (p + 1) & 1, wr = p & 1;
    const bool act = (layer == 0) ? (p < NSTEP) : (p >= 1);
    if (act) {
      const int t = (layer == 0) ? p : p - 1;
      // A operand: K 0..511 from (xs[t] | a), K 512..1023 from (h1 | h2)
      const unsigned short* A0 = (layer == 0) ? (xs + (size_t)t * 32768) : (ab + rd * 32768);
      const unsigned short* A1 = ((layer == 0) ? h1b : h2b) + rd * 32768;
      const unsigned short* rowA0 = A0 + (m0 + n) * NH;   // A-frag row = lane&15
      const unsigned short* rowA1 = A1 + (m0 + n) * NH;

      f32x4 acc[4];
#pragma unroll
      for (int g = 0; g < 4; ++g) acc[g] = (f32x4){bias_g[g], bias_g[g], bias_g[g], bias_g[g]};

#pragma unroll
      for (int s = 0; s < 32; ++s) {
        const unsigned short* ap = (s < 16) ? (rowA0 + s * 32 + q * 8)
                                            : (rowA1 + (s - 16) * 32 + q * 8);
        bf16x8 af = *(const bf16x8*)ap;
#pragma unroll
        for (int g = 0; g < 4; ++g) {
          bf16x8 bf = *(const bf16x8*)&wlds[((s * 4 + g) * 64 + lane) * 8];
          acc[g] = __builtin_amdgcn_mfma_f32_16x16x32_bf16(af, bf, acc[g], 0, 0, 0);
        }
      }

      // LSTM cell (gate order i,f,g,o), all lane-local
      float hv[4], sum = 0.f, ssq = 0.f;
#pragma unroll
      for (int r = 0; r < 4; ++r) {
        float ig = sigm(acc[0][r]), fg = sigm(acc[1][r]);
        float gg = tanhf(acc[2][r]), og = sigm(acc[3][r]);
        cst[r] = fg * cst[r] + ig * gg;
        hv[r] = og * tanhf(cst[r]);
        sum += hv[r]; ssq += hv[r] * hv[r];
      }
      // batch stats for feature f0+n: reduce over q (shfl) then waves (LDS)
      sum += __shfl_xor(sum, 16); ssq += __shfl_xor(ssq, 16);
      sum += __shfl_xor(sum, 32); ssq += __shfl_xor(ssq, 32);
      if (q == 0) { red[w][0][n] = sum; red[w][1][n] = ssq; }
      __syncthreads();
      float s1 = red[0][0][n] + red[1][0][n] + red[2][0][n] + red[3][0][n];
      float s2 = red[0][1][n] + red[1][1][n] + red[2][1][n] + red[3][1][n];
      float mu = s1 * (1.f / 64.f);
      float var = s2 * (1.f / 64.f) - mu * mu;
      float rs = rsqrtf(var + 1e-5f);

      unsigned short* hout = ((layer == 0) ? h1b : h2b) + wr * 32768;
      unsigned short* aout = (layer == 0) ? (ab + wr * 32768) : (bseq + (size_t)t * 32768);
#pragma unroll
      for (int r = 0; r < 4; ++r) {
        int row = m0 + q * 4 + r;
        float bn = (hv[r] - mu) * rs * gmv + btv;
        hout[row * NH + f0 + n] = f2bf(hv[r]);
        aout[row * NH + f0 + n] = f2bf(bn * mk[r]);
      }
    }

    if (p < NSTEP) {   // no barrier needed after the final phase (kernel-end flush covers k_dec)
      __threadfence();                 // release: make this phase's stores device-visible
      __syncthreads();                 // all waves of the block fenced
      if (threadIdx.x == 0) {
        __hip_atomic_fetch_add(&bar[p], 1u, __ATOMIC_RELAXED, __HIP_MEMORY_SCOPE_AGENT);
        while (__hip_atomic_load(&bar[p], __ATOMIC_RELAXED, __HIP_MEMORY_SCOPE_AGENT) < 64u)
          __builtin_amdgcn_s_sleep(2);
      }
      __syncthreads();                 // release the other waves
      __threadfence();                 // acquire: invalidate stale cached state
    }
  }
}

// ---------------- decoder GEMM ----------------
// out[b][v][t] = sum_h bseq[t][b][h]*wdec[v][h] + b_dec[v]
// block (nb, b): v-tile nb*128, batch b, all 128 t. Wave w: t rows [w*32, w*32+32).
__global__ void __launch_bounds__(256)
k_dec(const unsigned short* __restrict__ bseq, const unsigned short* __restrict__ wdec,
      const float* __restrict__ bdec, float* __restrict__ out) {
  const int nb = blockIdx.x, b = blockIdx.y;
  const int n0 = nb * 128;
  const int lane = threadIdx.x & 63, w = threadIdx.x >> 6;
  const int q = lane >> 4, n = lane & 15;

  f32x4 acc[2][8];
#pragma unroll
  for (int nt = 0; nt < 8; ++nt) {
    int v = n0 + nt * 16 + n;
    float bd = (v < NV) ? bdec[v] : 0.f;
#pragma unroll
    for (int mt = 0; mt < 2; ++mt) acc[mt][nt] = (f32x4){bd, bd, bd, bd};
  }
  const unsigned short* arow[2];
#pragma unroll
  for (int mt = 0; mt < 2; ++mt) {
    int t = w * 32 + mt * 16 + n;                       // A-frag row
    arow[mt] = bseq + ((size_t)t * NBATCH + b) * NH;
  }
  const unsigned short* brow[8];
#pragma unroll
  for (int nt = 0; nt < 8; ++nt) brow[nt] = wdec + (size_t)(n0 + nt * 16 + n) * NH;

#pragma unroll 4
  for (int s = 0; s < 16; ++s) {
    bf16x8 af[2];
#pragma unroll
    for (int mt = 0; mt < 2; ++mt) af[mt] = *(const bf16x8*)(arow[mt] + s * 32 + q * 8);
#pragma unroll
    for (int nt = 0; nt < 8; ++nt) {
      bf16x8 bf = *(const bf16x8*)(brow[nt] + s * 32 + q * 8);
#pragma unroll
      for (int mt = 0; mt < 2; ++mt)
        acc[mt][nt] = __builtin_amdgcn_mfma_f32_16x16x32_bf16(af[mt], bf, acc[mt][nt], 0, 0, 0);
    }
  }
  // store: lane's 4 acc regs = 4 consecutive t -> float4 (coalesced along t)
#pragma unroll
  for (int mt = 0; mt < 2; ++mt)
#pragma unroll
    for (int nt = 0; nt < 8; ++nt) {
      int v = n0 + nt * 16 + n;
      if (v < NV) {
        int t0 = w * 32 + mt * 16 + q * 4;
        *(f32x4*)(out + ((size_t)b * NV + v) * NSTEP + t0) = acc[mt][nt];
      }
    }
}

// ---------------- launch ----------------
extern "C" void kernel_launch(void* const* d_in, const int* in_sizes, int n_in,
                              void* d_out, int out_size, void* d_ws, size_t ws_size,
                              hipStream_t stream) {
  const int*   x     = (const int*)d_in[0];
  const float* emb   = (const float*)d_in[1];
  const float* Wih1  = (const float*)d_in[2];
  const float* Whh1  = (const float*)d_in[3];
  const float* bi1   = (const float*)d_in[4];
  const float* bh1   = (const float*)d_in[5];
  const float* g1    = (const float*)d_in[6];
  const float* be1   = (const float*)d_in[7];
  const float* m1    = (const float*)d_in[8];
  const float* Wih2  = (const float*)d_in[9];
  const float* Whh2  = (const float*)d_in[10];
  const float* bi2   = (const float*)d_in[11];
  const float* bh2   = (const float*)d_in[12];
  const float* g2    = (const float*)d_in[13];
  const float* be2   = (const float*)d_in[14];
  const float* m2    = (const float*)d_in[15];
  const float* Wdec  = (const float*)d_in[16];
  const float* bdec  = (const float*)d_in[17];
  float* out = (float*)d_out;
  char* ws = (char*)d_ws;

  unsigned short* xs    = (unsigned short*)(ws + OFF_XS);
  unsigned short* wp    = (unsigned short*)(ws + OFF_WP);
  unsigned short* wdec  = (unsigned short*)(ws + OFF_WDEC);
  float*          bias  = (float*)(ws + OFF_BIAS);
  unsigned short* state = (unsigned short*)(ws + OFF_STATE);
  unsigned short* bseq  = (unsigned short*)(ws + OFF_BSEQ);
  unsigned*       bar   = (unsigned*)(ws + OFF_BAR);

  // zero LSTM state double-buffers + barrier counters (ws is poisoned 0xAA before every call)
  hipMemsetAsync(state, 0, SZ_STATE, stream);
  hipMemsetAsync(bar, 0, SZ_BAR, stream);

  k_xs   <<<dim3(16384), dim3(256), 0, stream>>>(x, emb, xs);
  k_wdec <<<dim3(16128), dim3(256), 0, stream>>>(Wdec, wdec);
  k_bias <<<dim3(16),    dim3(256), 0, stream>>>(bi1, bh1, bi2, bh2, bias);
  k_wpack<<<dim3(2048),  dim3(256), 0, stream>>>(Wih1, Whh1, Wih2, Whh2, wp);

  void* kargs[] = {(void*)&xs, (void*)&wp, (void*)&bias,
                   (void*)&g1, (void*)&be1, (void*)&m1,
                   (void*)&g2, (void*)&be2, (void*)&m2,
                   (void*)&state, (void*)&bseq, (void*)&bar};
  hipLaunchCooperativeKernel((void*)k_recur, dim3(64), dim3(256), kargs, 0, stream);

  k_dec<<<dim3(63, 64), dim3(256), 0, stream>>>(bseq, wdec, bdec, out);
}